// Round 14
// baseline (322.076 us; speedup 1.0000x reference)
//
#include <hip/hip_runtime.h>
#include <hip/hip_fp16.h>

#define DIM 64
#define BSH 8            // bucket = row >> 8  (256 rows per bucket)
#define MAXNB 1024       // bucket-count cap (nn <= 256K)
#define NSH 8            // XCD shards (blockIdx&7 ~ round-robin XCD dispatch)
#define SBIN_SH 1536     // bin slots per (bucket,shard): item shard mean 1024 + 16 sigma
#define SCSR 12288       // fixed csr slots per bucket (max ~10K entries + 256*7 pad)

// ---------- gcur[(k<<3)+s] = region base ----------
__global__ void init_gcur(int* __restrict__ gcur, int n) {
    int i = blockIdx.x * blockDim.x + threadIdx.x;
    if (i < n) gcur[i] = i * SBIN_SH;
}

// ---------- A2: LDS histogram -> per-(block,bucket) claim on SHARD counters -> scatter ----------
// R9 PMC (256-thr version): Occupancy 36%, VALUBusy 1.9%, HBM 16% -> scatter is
// WAVE-STARVED latency-bound. 512 threads x 1024 blocks = 4 blocks/CU x 8 waves
// = 32 waves/CU (100%) -> 2x scattered stores in flight. Claim-chain depth unchanged.
__global__ __launch_bounds__(512) void binA2_claim(
        const int* __restrict__ row, const int* __restrict__ col,
        int* __restrict__ gcur, unsigned int* __restrict__ bin,
        int ne, int chunk, int nbk) {
    __shared__ int hcnt[MAXNB];
    __shared__ int cur[MAXNB];
    int t = threadIdx.x;
    int s = blockIdx.x & (NSH - 1);
    for (int k = t; k < nbk; k += 512) hcnt[k] = 0;
    __syncthreads();
    int start = blockIdx.x * chunk, end = min(ne, start + chunk);
    for (int i = start + t; i < end; i += 512)
        atomicAdd(&hcnt[row[i] >> BSH], 1);
    __syncthreads();
    for (int k = t; k < nbk; k += 512) {
        int c = hcnt[k];
        cur[k] = (c > 0) ? atomicAdd(&gcur[(k << 3) + s], c) : 0;
    }
    __syncthreads();
    for (int i = start + t; i < end; i += 512) {
        int r = row[i];
        int k = r >> BSH;
        int p = atomicAdd(&cur[k], 1);
        if (p < ((k << 3) + s + 1) * SBIN_SH)   // overflow guard: drop instead of corrupt
            bin[p] = ((unsigned)(r & 255) << 24) | (unsigned)col[i];
    }
}

// ---------- B: per-bucket CSR build from 8 shard segments, direct global scatter ----------
// 1024 threads (16 waves/block, 2 blocks/CU = full occupancy): covers the latency of
// the coalesced count/place passes that 8 waves could not.
__global__ __launch_bounds__(1024) void csr_build(
        const unsigned int* __restrict__ bin, const int* __restrict__ gcur,
        int* __restrict__ csr, int* __restrict__ cnt, int* __restrict__ roff,
        float* __restrict__ dinv, float* __restrict__ sqd, int nn) {
    __shared__ int rc[256];
    __shared__ int sc[256];
    __shared__ int rcur[256];
    int k = blockIdx.x;
    int t = threadIdx.x;
    int cbase = k * SCSR;
    if (t < 256) rc[t] = 0;
    __syncthreads();
    // pass 1: count rows over the 8 contiguous shard segments
    for (int s = 0; s < NSH; ++s) {
        int sb = ((k << 3) + s) * SBIN_SH;
        int len = min(gcur[(k << 3) + s] - sb, SBIN_SH);
        for (int i = t; i < len; i += 1024)
            atomicAdd(&rc[bin[sb + i] >> 24], 1);
    }
    __syncthreads();
    int w = 0;
    if (t < 256) {
        w = (rc[t] + 7) & ~7;
        sc[t] = w;
    }
    __syncthreads();
    for (int d = 1; d < 256; d <<= 1) {
        int v = (t >= d && t < 256) ? sc[t - d] : 0;
        __syncthreads();
        if (t < 256) sc[t] += v;
        __syncthreads();
    }
    if (t < 256) {
        int myoff = sc[t] - w;
        rcur[t] = myoff;
        int r = (k << BSH) + t;
        if (r < nn) {
            int d = rc[t];
            cnt[r] = d;
            roff[r] = cbase + myoff;
            dinv[r] = d > 0 ? rsqrtf((float)d) : 0.0f;
            sqd[r]  = d > 0 ? sqrtf((float)d)  : 0.0f;
        }
    }
    __syncthreads();
    // pass 2: place directly to global (L2-hot ~48KB window)
    for (int s = 0; s < NSH; ++s) {
        int sb = ((k << 3) + s) * SBIN_SH;
        int len = min(gcur[(k << 3) + s] - sb, SBIN_SH);
        for (int i = t; i < len; i += 1024) {
            unsigned u = bin[sb + i];
            int p = atomicAdd(&rcur[u >> 24], 1);
            csr[cbase + p] = (int)(u & 0xFFFFFFu);
        }
    }
    __syncthreads();
    // pad own row's gap slots (<=7) with sentinel
    if (t < 256) {
        int endp = rcur[t];            // == myoff + rc[t]
        int endw = sc[t];              // == myoff + w
        for (int p = endp; p < endw; ++p) csr[cbase + p] = nn;
    }
}

// ---------- mark rows whose y2 is consumed: batch rows + their neighbors ----------
__global__ void mark_kernel(const int* __restrict__ cnt, const int* __restrict__ off,
                            const int* __restrict__ csr, const int* __restrict__ uidx,
                            const int* __restrict__ iidx, unsigned char* __restrict__ flag,
                            int nb, int nu) {
    int t = blockIdx.x * (blockDim.x >> 6) + (threadIdx.x >> 6);
    int lane = threadIdx.x & 63;
    if (t >= 2 * nb) return;
    int r = (t < nb) ? uidx[t] : nu + iidx[t - nb];
    if (lane == 0) flag[r] = 1;
    int e = cnt[r];
    const int* erow = csr + off[r];
    for (int j = lane; j < e; j += 64) flag[erow[j]] = 1;
}

// ---------- init: y0[r] = half(dinv[r] * emb[r]); sentinel row nn zeroed in BOTH ----------
__global__ void init_y_kernel(const float2* __restrict__ ue2, const float2* __restrict__ ie2,
                              const float* __restrict__ dinv, __half2* __restrict__ ya,
                              __half2* __restrict__ yb, int nu, int nn) {
    int t = blockIdx.x * blockDim.x + threadIdx.x;
    if (t >= (nn + 1) * 32) return;
    int r = t >> 5;
    if (r >= nn) {   // sentinel zero row
        ya[t] = __floats2half2_rn(0.0f, 0.0f);
        yb[t] = __floats2half2_rn(0.0f, 0.0f);
        return;
    }
    float2 v = (r < nu) ? ue2[t] : ie2[t - nu * 32];
    float d = dinv[r];
    ya[t] = __floats2half2_rn(d * v.x, d * v.y);
}

// ---------- paired-half2 gather-SpMM, 16-edge unrolled: 8 gathers in flight ----------
__global__ void spmm_half_kernel(const int* __restrict__ cnt, const int* __restrict__ off,
                                 const int* __restrict__ csr, const float* __restrict__ dinv,
                                 const __half2* __restrict__ y2, __half2* __restrict__ yn2,
                                 const unsigned char* __restrict__ flag, int nn) {
    int r = blockIdx.x * 4 + (threadIdx.x >> 6);
    if (r >= nn) return;
    if (flag && !flag[r]) return;
    int lane = threadIdx.x & 63;
    int h = lane >> 5;
    int f = lane & 31;
    int e = cnt[r];
    const int* erow = csr + off[r];
    float2 a0 = {0.f, 0.f}, a1 = {0.f, 0.f}, a2 = {0.f, 0.f}, a3 = {0.f, 0.f};
    int j = 0;
    for (; j + 16 <= e; j += 16) {
        int4 ca = *(const int4*)(erow + j);
        int4 cb = *(const int4*)(erow + j + 4);
        int4 cc = *(const int4*)(erow + j + 8);
        int4 cd = *(const int4*)(erow + j + 12);
        int c0 = h ? ca.y : ca.x, c1 = h ? ca.w : ca.z;
        int c2 = h ? cb.y : cb.x, c3 = h ? cb.w : cb.z;
        int c4 = h ? cc.y : cc.x, c5 = h ? cc.w : cc.z;
        int c6 = h ? cd.y : cd.x, c7 = h ? cd.w : cd.z;
        float2 p0 = __half22float2(y2[(size_t)c0 * 32 + f]);
        float2 p1 = __half22float2(y2[(size_t)c1 * 32 + f]);
        float2 p2 = __half22float2(y2[(size_t)c2 * 32 + f]);
        float2 p3 = __half22float2(y2[(size_t)c3 * 32 + f]);
        float2 p4 = __half22float2(y2[(size_t)c4 * 32 + f]);
        float2 p5 = __half22float2(y2[(size_t)c5 * 32 + f]);
        float2 p6 = __half22float2(y2[(size_t)c6 * 32 + f]);
        float2 p7 = __half22float2(y2[(size_t)c7 * 32 + f]);
        a0.x += p0.x + p4.x; a0.y += p0.y + p4.y;
        a1.x += p1.x + p5.x; a1.y += p1.y + p5.y;
        a2.x += p2.x + p6.x; a2.y += p2.y + p6.y;
        a3.x += p3.x + p7.x; a3.y += p3.y + p7.y;
    }
    for (; j < e; j += 8) {   // 0..2 iterations of 8 (sentinel-padded)
        int4 ca = *(const int4*)(erow + j);
        int4 cb = *(const int4*)(erow + j + 4);
        int c0 = h ? ca.y : ca.x, c1 = h ? ca.w : ca.z;
        int c2 = h ? cb.y : cb.x, c3 = h ? cb.w : cb.z;
        float2 p0 = __half22float2(y2[(size_t)c0 * 32 + f]);
        float2 p1 = __half22float2(y2[(size_t)c1 * 32 + f]);
        float2 p2 = __half22float2(y2[(size_t)c2 * 32 + f]);
        float2 p3 = __half22float2(y2[(size_t)c3 * 32 + f]);
        a0.x += p0.x; a0.y += p0.y;
        a1.x += p1.x; a1.y += p1.y;
        a2.x += p2.x; a2.y += p2.y;
        a3.x += p3.x; a3.y += p3.y;
    }
    float sx = (a0.x + a1.x) + (a2.x + a3.x);
    float sy = (a0.y + a1.y) + (a2.y + a3.y);
    sx += __shfl_xor(sx, 32);
    sy += __shfl_xor(sy, 32);
    if (h == 0) {
        float d = dinv[r];
        float d2 = d * d;
        yn2[(size_t)r * 32 + f] = __floats2half2_rn(d2 * sx, d2 * sy);
    }
}

// ---------- layer-3 restricted to the 2*nb batch rows, same paired+unrolled structure ----------
__global__ void spmm_rows_acc_kernel(const int* __restrict__ cnt, const int* __restrict__ off,
                                     const int* __restrict__ csr, const float* __restrict__ dinv,
                                     const __half2* __restrict__ y2, const int* __restrict__ uidx,
                                     const int* __restrict__ iidx, float2* __restrict__ acc2,
                                     int nb, int nu) {
    int t = blockIdx.x * 4 + (threadIdx.x >> 6);
    if (t >= 2 * nb) return;
    int lane = threadIdx.x & 63;
    int h = lane >> 5;
    int f = lane & 31;
    int r = (t < nb) ? uidx[t] : nu + iidx[t - nb];
    int e = cnt[r];
    const int* erow = csr + off[r];
    float2 a0 = {0.f, 0.f}, a1 = {0.f, 0.f}, a2 = {0.f, 0.f}, a3 = {0.f, 0.f};
    int j = 0;
    for (; j + 16 <= e; j += 16) {
        int4 ca = *(const int4*)(erow + j);
        int4 cb = *(const int4*)(erow + j + 4);
        int4 cc = *(const int4*)(erow + j + 8);
        int4 cd = *(const int4*)(erow + j + 12);
        int c0 = h ? ca.y : ca.x, c1 = h ? ca.w : ca.z;
        int c2 = h ? cb.y : cb.x, c3 = h ? cb.w : cb.z;
        int c4 = h ? cc.y : cc.x, c5 = h ? cc.w : cc.z;
        int c6 = h ? cd.y : cd.x, c7 = h ? cd.w : cd.z;
        float2 p0 = __half22float2(y2[(size_t)c0 * 32 + f]);
        float2 p1 = __half22float2(y2[(size_t)c1 * 32 + f]);
        float2 p2 = __half22float2(y2[(size_t)c2 * 32 + f]);
        float2 p3 = __half22float2(y2[(size_t)c3 * 32 + f]);
        float2 p4 = __half22float2(y2[(size_t)c4 * 32 + f]);
        float2 p5 = __half22float2(y2[(size_t)c5 * 32 + f]);
        float2 p6 = __half22float2(y2[(size_t)c6 * 32 + f]);
        float2 p7 = __half22float2(y2[(size_t)c7 * 32 + f]);
        a0.x += p0.x + p4.x; a0.y += p0.y + p4.y;
        a1.x += p1.x + p5.x; a1.y += p1.y + p5.y;
        a2.x += p2.x + p6.x; a2.y += p2.y + p6.y;
        a3.x += p3.x + p7.x; a3.y += p3.y + p7.y;
    }
    for (; j < e; j += 8) {
        int4 ca = *(const int4*)(erow + j);
        int4 cb = *(const int4*)(erow + j + 4);
        int c0 = h ? ca.y : ca.x, c1 = h ? ca.w : ca.z;
        int c2 = h ? cb.y : cb.x, c3 = h ? cb.w : cb.z;
        float2 p0 = __half22float2(y2[(size_t)c0 * 32 + f]);
        float2 p1 = __half22float2(y2[(size_t)c1 * 32 + f]);
        float2 p2 = __half22float2(y2[(size_t)c2 * 32 + f]);
        float2 p3 = __half22float2(y2[(size_t)c3 * 32 + f]);
        a0.x += p0.x; a0.y += p0.y;
        a1.x += p1.x; a1.y += p1.y;
        a2.x += p2.x; a2.y += p2.y;
        a3.x += p3.x; a3.y += p3.y;
    }
    float sx = (a0.x + a1.x) + (a2.x + a3.x);
    float sy = (a0.y + a1.y) + (a2.y + a3.y);
    sx += __shfl_xor(sx, 32);
    sy += __shfl_xor(sy, 32);
    if (h == 0) {
        float d = dinv[r];
        float2 v = acc2[(size_t)t * 32 + f];
        v.x += d * sx;
        v.y += d * sy;
        acc2[(size_t)t * 32 + f] = v;
    }
}

// ---------- layer-0 acc: read embeddings directly (fp32 exact), first write ----------
__global__ void gather_acc0(const float* __restrict__ ue, const float* __restrict__ ie,
                            const int* __restrict__ uidx, const int* __restrict__ iidx,
                            float* __restrict__ acc, int nb, int nu) {
    int t = blockIdx.x * blockDim.x + threadIdx.x;
    int b = t >> 6;
    int lane = t & 63;
    if (b < nb) acc[t] = ue[(long)uidx[b] * DIM + lane];
    else if (b < 2 * nb) acc[t] = ie[(long)iidx[b - nb] * DIM + lane];
}

// ---------- layers 1,2 acc: x_l[r] = y_l[r] * sqrt(deg_r), half2-vectorized ----------
__global__ void gather_acc_y(const __half2* __restrict__ y2, const float* __restrict__ sqd,
                             const int* __restrict__ uidx, const int* __restrict__ iidx,
                             float2* __restrict__ acc2, int nb, int nu) {
    int t = blockIdx.x * blockDim.x + threadIdx.x;
    if (t >= 2 * nb * 32) return;
    int b = t >> 5;
    int r = (b < nb) ? uidx[b] : nu + iidx[b - nb];
    float s = sqd[r];
    float2 v = __half22float2(y2[(size_t)r * 32 + (t & 31)]);
    float2 a = acc2[t];
    a.x += v.x * s;
    a.y += v.y * s;
    acc2[t] = a;
}

// scores[b] = dot(acc_u[b], acc_i[b]) / 16
__global__ void scores_kernel(const float* __restrict__ acc, float* __restrict__ out, int nb) {
    int b = blockIdx.x * (blockDim.x >> 6) + (threadIdx.x >> 6);
    int lane = threadIdx.x & 63;
    if (b >= nb) return;
    float p = acc[(long)b * DIM + lane] * acc[(long)(nb + b) * DIM + lane];
    #pragma unroll
    for (int off = 32; off; off >>= 1) p += __shfl_down(p, off);
    if (lane == 0) out[b] = p * 0.0625f;
}

extern "C" void kernel_launch(void* const* d_in, const int* in_sizes, int n_in,
                              void* d_out, int out_size, void* d_ws, size_t ws_size,
                              hipStream_t stream) {
    const float* user_emb = (const float*)d_in[0];
    const float* item_emb = (const float*)d_in[1];
    const int* edge_row = (const int*)d_in[2];
    const int* edge_col = (const int*)d_in[3];
    const int* user_idx = (const int*)d_in[4];
    const int* item_idx = (const int*)d_in[5];
    float* out = (float*)d_out;

    const int nu = in_sizes[0] / DIM;   // 100000
    const int ni = in_sizes[1] / DIM;   // 50000
    const int nn = nu + ni;             // 150000
    const int ne = in_sizes[2];         // 3200000
    const int nb = in_sizes[4];         // 4096

    const int nbk = (nn + 255) >> BSH;              // 586 buckets
    const int NBLKA = 1024;
    const int chunk = (ne + NBLKA - 1) / NBLKA;     // 3125

    char* ws = (char*)d_ws;
    size_t off_b = 0;
    auto alloc = [&](size_t bytes) -> void* {
        void* p = ws + off_b;
        off_b = (off_b + bytes + 255) & ~(size_t)255;
        return p;
    };

    int*   cnt     = (int*)  alloc((size_t)nn * 4);
    int*   roff    = (int*)  alloc((size_t)nn * 4);
    float* dinv    = (float*)alloc((size_t)nn * 4);
    float* sqd     = (float*)alloc((size_t)nn * 4);
    unsigned char* flag = (unsigned char*)alloc((size_t)nn);
    int*   gcur    = (int*)  alloc((size_t)MAXNB * NSH * 4);
    int*   csr     = (int*)  alloc((size_t)nbk * SCSR * 4);
    // bin (shard-partitioned, consumed by csr_build) unioned with ya (written after)
    size_t bin_bytes = (size_t)nbk * NSH * SBIN_SH * 4;   // ~28.8 MB
    size_t y_bytes   = (size_t)(nn + 1) * DIM * 2;        // +1 sentinel zero row
    char*  uni     = (char*) alloc(bin_bytes > y_bytes ? bin_bytes : y_bytes);
    unsigned int* bin = (unsigned int*)uni;
    __half2* ya    = (__half2*)uni;
    __half2* yb    = (__half2*)alloc(y_bytes);
    float* acc     = (float*)alloc((size_t)2 * nb * DIM * 4);

    hipMemsetAsync(flag, 0, (size_t)nn, stream);

    // --- binned CSR build: XCD-sharded claim binning, full-occupancy kernels ---
    init_gcur<<<(nbk * NSH + 255) / 256, 256, 0, stream>>>(gcur, nbk * NSH);
    binA2_claim<<<NBLKA, 512, 0, stream>>>(edge_row, edge_col, gcur, bin, ne, chunk, nbk);
    csr_build<<<nbk, 1024, 0, stream>>>(bin, gcur, csr, cnt, roff, dinv, sqd, nn);

    // --- mark rows whose y2 is consumed (batch + neighbors) ---
    mark_kernel<<<(2 * nb + 3) / 4, 256, 0, stream>>>(cnt, roff, csr, user_idx, item_idx,
                                                      flag, nb, nu);

    // --- init y0 = half(dinv * emb); zero sentinel rows (overwrites bin region) ---
    init_y_kernel<<<((nn + 1) * 32 + 255) / 256, 256, 0, stream>>>(
        (const float2*)user_emb, (const float2*)item_emb, dinv, ya, yb, nu, nn);

    // --- layer 0 acc: exact fp32 embeddings ---
    gather_acc0<<<(2 * nb * DIM + 255) / 256, 256, 0, stream>>>(
        user_emb, item_emb, user_idx, item_idx, acc, nb, nu);

    // --- layer 1 (full) ---
    spmm_half_kernel<<<(nn + 3) / 4, 256, 0, stream>>>(cnt, roff, csr, dinv, ya, yb,
                                                       (const unsigned char*)nullptr, nn);
    gather_acc_y<<<(2 * nb * 32 + 255) / 256, 256, 0, stream>>>(
        yb, sqd, user_idx, item_idx, (float2*)acc, nb, nu);

    // --- layer 2 (restricted to flagged ~69% of rows) ---
    spmm_half_kernel<<<(nn + 3) / 4, 256, 0, stream>>>(cnt, roff, csr, dinv, yb, ya, flag, nn);
    gather_acc_y<<<(2 * nb * 32 + 255) / 256, 256, 0, stream>>>(
        ya, sqd, user_idx, item_idx, (float2*)acc, nb, nu);

    // --- layer 3: only the 8192 batch rows are ever read -> mini-SpMM into acc ---
    spmm_rows_acc_kernel<<<(2 * nb + 3) / 4, 256, 0, stream>>>(
        cnt, roff, csr, dinv, ya, user_idx, item_idx, (float2*)acc, nb, nu);

    scores_kernel<<<(nb + 3) / 4, 256, 0, stream>>>(acc, out, nb);
}

// Round 15
// 313.736 us; speedup vs baseline: 1.0266x; 1.0266x over previous
//
#include <hip/hip_runtime.h>
#include <hip/hip_fp16.h>

#define DIM 64
#define BSH 8            // bucket = row >> 8  (256 rows per bucket)
#define MAXNB 1024       // bucket-count cap (nn <= 256K)
#define NSH 8            // XCD shards (blockIdx&7 ~ round-robin XCD dispatch)
#define NBLKA 1024       // binning blocks; 128 per shard
#define SBIN_SH 1536     // bin slots per (bucket,shard): item shard mean 1024 + 16 sigma
#define SCSR 12288       // fixed csr slots per bucket (max ~10K entries + 256*7 pad)

// ---------- A1s: per-block bucket histogram -> shard-major blkoff[(k*8+s)*128 + b/8] ----------
// Deterministic replacement for R13's claim phase (128-deep same-address atomic chains
// ~ 500cy each = ~27us wall floor, per R10's measurement). 2.4MB table, L2-resident.
__global__ void binA1s(const int* __restrict__ row, int* __restrict__ blkoff,
                       int ne, int chunk, int nbk) {
    __shared__ int h[MAXNB];
    for (int k = threadIdx.x; k < nbk; k += 256) h[k] = 0;
    __syncthreads();
    int b = blockIdx.x;
    int start = b * chunk, end = min(ne, start + chunk);
    for (int i = start + threadIdx.x; i < end; i += 256)
        atomicAdd(&h[row[i] >> BSH], 1);
    __syncthreads();
    int s = b & (NSH - 1), g = b >> 3;
    for (int k = threadIdx.x; k < nbk; k += 256)
        blkoff[(size_t)((k << 3) + s) * 128 + g] = h[k];
}

// ---------- scanS: per-(bucket,shard) exclusive scan over its 128 block counts ----------
// Fully coalesced 512B read/write per block. Zero global atomics.
__global__ void scanS(int* __restrict__ blkoff, int* __restrict__ tot) {
    __shared__ int sdat[128];
    int p = blockIdx.x;
    int t = threadIdx.x;
    int v = blkoff[(size_t)p * 128 + t];
    sdat[t] = v;
    __syncthreads();
    for (int d = 1; d < 128; d <<= 1) {
        int u = (t >= d) ? sdat[t - d] : 0;
        __syncthreads();
        sdat[t] += u;
        __syncthreads();
    }
    blkoff[(size_t)p * 128 + t] = sdat[t] - v;   // exclusive
    if (t == 127) tot[p] = sdat[127];
}

// ---------- A2s: scatter edges into sharded bucket regions (exact offsets, LDS cursors) ----------
// No claim phase; bin lines single-shard (R13's layout). Exact offsets -> no overflow guard.
__global__ void binA2s(const int* __restrict__ row, const int* __restrict__ col,
                       const int* __restrict__ blkoff, unsigned int* __restrict__ bin,
                       int ne, int chunk, int nbk) {
    __shared__ int cur[MAXNB];
    int b = blockIdx.x;
    int s = b & (NSH - 1), g = b >> 3;
    for (int k = threadIdx.x; k < nbk; k += 256) {
        int p = (k << 3) + s;
        cur[k] = p * SBIN_SH + blkoff[(size_t)p * 128 + g];
    }
    __syncthreads();
    int start = b * chunk, end = min(ne, start + chunk);
    for (int i = start + threadIdx.x; i < end; i += 256) {
        int r = row[i];
        int p = atomicAdd(&cur[r >> BSH], 1);   // LDS atomic only
        bin[p] = ((unsigned)(r & 255) << 24) | (unsigned)col[i];
    }
}

// ---------- B: per-bucket CSR build from 8 shard segments, direct global scatter ----------
// R13's proven 512-thread config (R14's 1024 was neutral-to-worse).
__global__ __launch_bounds__(512) void csr_build(
        const unsigned int* __restrict__ bin, const int* __restrict__ tot,
        int* __restrict__ csr, int* __restrict__ cnt, int* __restrict__ roff,
        float* __restrict__ dinv, float* __restrict__ sqd, int nn) {
    __shared__ int rc[256];
    __shared__ int sc[256];
    __shared__ int rcur[256];
    int k = blockIdx.x;
    int t = threadIdx.x;
    int cbase = k * SCSR;
    if (t < 256) rc[t] = 0;
    __syncthreads();
    // pass 1: count rows over the 8 contiguous shard segments
    for (int s = 0; s < NSH; ++s) {
        int p = (k << 3) + s;
        int sb = p * SBIN_SH;
        int len = min(tot[p], SBIN_SH);
        for (int i = t; i < len; i += 512)
            atomicAdd(&rc[bin[sb + i] >> 24], 1);
    }
    __syncthreads();
    int w = 0;
    if (t < 256) {
        w = (rc[t] + 7) & ~7;
        sc[t] = w;
    }
    __syncthreads();
    for (int d = 1; d < 256; d <<= 1) {
        int v = (t >= d && t < 256) ? sc[t - d] : 0;
        __syncthreads();
        if (t < 256) sc[t] += v;
        __syncthreads();
    }
    if (t < 256) {
        int myoff = sc[t] - w;
        rcur[t] = myoff;
        int r = (k << BSH) + t;
        if (r < nn) {
            int d = rc[t];
            cnt[r] = d;
            roff[r] = cbase + myoff;
            dinv[r] = d > 0 ? rsqrtf((float)d) : 0.0f;
            sqd[r]  = d > 0 ? sqrtf((float)d)  : 0.0f;
        }
    }
    __syncthreads();
    // pass 2: place directly to global (L2-hot ~48KB window)
    for (int s = 0; s < NSH; ++s) {
        int p = (k << 3) + s;
        int sb = p * SBIN_SH;
        int len = min(tot[p], SBIN_SH);
        for (int i = t; i < len; i += 512) {
            unsigned u = bin[sb + i];
            int q = atomicAdd(&rcur[u >> 24], 1);
            csr[cbase + q] = (int)(u & 0xFFFFFFu);
        }
    }
    __syncthreads();
    // pad own row's gap slots (<=7) with sentinel
    if (t < 256) {
        int endp = rcur[t];            // == myoff + rc[t]
        int endw = sc[t];              // == myoff + w
        for (int q = endp; q < endw; ++q) csr[cbase + q] = nn;
    }
}

// ---------- mark rows whose y2 is consumed: batch rows + their neighbors ----------
__global__ void mark_kernel(const int* __restrict__ cnt, const int* __restrict__ off,
                            const int* __restrict__ csr, const int* __restrict__ uidx,
                            const int* __restrict__ iidx, unsigned char* __restrict__ flag,
                            int nb, int nu) {
    int t = blockIdx.x * (blockDim.x >> 6) + (threadIdx.x >> 6);
    int lane = threadIdx.x & 63;
    if (t >= 2 * nb) return;
    int r = (t < nb) ? uidx[t] : nu + iidx[t - nb];
    if (lane == 0) flag[r] = 1;
    int e = cnt[r];
    const int* erow = csr + off[r];
    for (int j = lane; j < e; j += 64) flag[erow[j]] = 1;
}

// ---------- init: y0[r] = half(dinv[r] * emb[r]); sentinel row nn zeroed in BOTH ----------
__global__ void init_y_kernel(const float2* __restrict__ ue2, const float2* __restrict__ ie2,
                              const float* __restrict__ dinv, __half2* __restrict__ ya,
                              __half2* __restrict__ yb, int nu, int nn) {
    int t = blockIdx.x * blockDim.x + threadIdx.x;
    if (t >= (nn + 1) * 32) return;
    int r = t >> 5;
    if (r >= nn) {   // sentinel zero row
        ya[t] = __floats2half2_rn(0.0f, 0.0f);
        yb[t] = __floats2half2_rn(0.0f, 0.0f);
        return;
    }
    float2 v = (r < nu) ? ue2[t] : ie2[t - nu * 32];
    float d = dinv[r];
    ya[t] = __floats2half2_rn(d * v.x, d * v.y);
}

// ---------- paired-half2 gather-SpMM, 16-edge unrolled: 8 gathers in flight ----------
__global__ void spmm_half_kernel(const int* __restrict__ cnt, const int* __restrict__ off,
                                 const int* __restrict__ csr, const float* __restrict__ dinv,
                                 const __half2* __restrict__ y2, __half2* __restrict__ yn2,
                                 const unsigned char* __restrict__ flag, int nn) {
    int r = blockIdx.x * 4 + (threadIdx.x >> 6);
    if (r >= nn) return;
    if (flag && !flag[r]) return;
    int lane = threadIdx.x & 63;
    int h = lane >> 5;
    int f = lane & 31;
    int e = cnt[r];
    const int* erow = csr + off[r];
    float2 a0 = {0.f, 0.f}, a1 = {0.f, 0.f}, a2 = {0.f, 0.f}, a3 = {0.f, 0.f};
    int j = 0;
    for (; j + 16 <= e; j += 16) {
        int4 ca = *(const int4*)(erow + j);
        int4 cb = *(const int4*)(erow + j + 4);
        int4 cc = *(const int4*)(erow + j + 8);
        int4 cd = *(const int4*)(erow + j + 12);
        int c0 = h ? ca.y : ca.x, c1 = h ? ca.w : ca.z;
        int c2 = h ? cb.y : cb.x, c3 = h ? cb.w : cb.z;
        int c4 = h ? cc.y : cc.x, c5 = h ? cc.w : cc.z;
        int c6 = h ? cd.y : cd.x, c7 = h ? cd.w : cd.z;
        float2 p0 = __half22float2(y2[(size_t)c0 * 32 + f]);
        float2 p1 = __half22float2(y2[(size_t)c1 * 32 + f]);
        float2 p2 = __half22float2(y2[(size_t)c2 * 32 + f]);
        float2 p3 = __half22float2(y2[(size_t)c3 * 32 + f]);
        float2 p4 = __half22float2(y2[(size_t)c4 * 32 + f]);
        float2 p5 = __half22float2(y2[(size_t)c5 * 32 + f]);
        float2 p6 = __half22float2(y2[(size_t)c6 * 32 + f]);
        float2 p7 = __half22float2(y2[(size_t)c7 * 32 + f]);
        a0.x += p0.x + p4.x; a0.y += p0.y + p4.y;
        a1.x += p1.x + p5.x; a1.y += p1.y + p5.y;
        a2.x += p2.x + p6.x; a2.y += p2.y + p6.y;
        a3.x += p3.x + p7.x; a3.y += p3.y + p7.y;
    }
    for (; j < e; j += 8) {   // 0..2 iterations of 8 (sentinel-padded)
        int4 ca = *(const int4*)(erow + j);
        int4 cb = *(const int4*)(erow + j + 4);
        int c0 = h ? ca.y : ca.x, c1 = h ? ca.w : ca.z;
        int c2 = h ? cb.y : cb.x, c3 = h ? cb.w : cb.z;
        float2 p0 = __half22float2(y2[(size_t)c0 * 32 + f]);
        float2 p1 = __half22float2(y2[(size_t)c1 * 32 + f]);
        float2 p2 = __half22float2(y2[(size_t)c2 * 32 + f]);
        float2 p3 = __half22float2(y2[(size_t)c3 * 32 + f]);
        a0.x += p0.x; a0.y += p0.y;
        a1.x += p1.x; a1.y += p1.y;
        a2.x += p2.x; a2.y += p2.y;
        a3.x += p3.x; a3.y += p3.y;
    }
    float sx = (a0.x + a1.x) + (a2.x + a3.x);
    float sy = (a0.y + a1.y) + (a2.y + a3.y);
    sx += __shfl_xor(sx, 32);
    sy += __shfl_xor(sy, 32);
    if (h == 0) {
        float d = dinv[r];
        float d2 = d * d;
        yn2[(size_t)r * 32 + f] = __floats2half2_rn(d2 * sx, d2 * sy);
    }
}

// ---------- layer-3 restricted to the 2*nb batch rows, same paired+unrolled structure ----------
__global__ void spmm_rows_acc_kernel(const int* __restrict__ cnt, const int* __restrict__ off,
                                     const int* __restrict__ csr, const float* __restrict__ dinv,
                                     const __half2* __restrict__ y2, const int* __restrict__ uidx,
                                     const int* __restrict__ iidx, float2* __restrict__ acc2,
                                     int nb, int nu) {
    int t = blockIdx.x * 4 + (threadIdx.x >> 6);
    if (t >= 2 * nb) return;
    int lane = threadIdx.x & 63;
    int h = lane >> 5;
    int f = lane & 31;
    int r = (t < nb) ? uidx[t] : nu + iidx[t - nb];
    int e = cnt[r];
    const int* erow = csr + off[r];
    float2 a0 = {0.f, 0.f}, a1 = {0.f, 0.f}, a2 = {0.f, 0.f}, a3 = {0.f, 0.f};
    int j = 0;
    for (; j + 16 <= e; j += 16) {
        int4 ca = *(const int4*)(erow + j);
        int4 cb = *(const int4*)(erow + j + 4);
        int4 cc = *(const int4*)(erow + j + 8);
        int4 cd = *(const int4*)(erow + j + 12);
        int c0 = h ? ca.y : ca.x, c1 = h ? ca.w : ca.z;
        int c2 = h ? cb.y : cb.x, c3 = h ? cb.w : cb.z;
        int c4 = h ? cc.y : cc.x, c5 = h ? cc.w : cc.z;
        int c6 = h ? cd.y : cd.x, c7 = h ? cd.w : cd.z;
        float2 p0 = __half22float2(y2[(size_t)c0 * 32 + f]);
        float2 p1 = __half22float2(y2[(size_t)c1 * 32 + f]);
        float2 p2 = __half22float2(y2[(size_t)c2 * 32 + f]);
        float2 p3 = __half22float2(y2[(size_t)c3 * 32 + f]);
        float2 p4 = __half22float2(y2[(size_t)c4 * 32 + f]);
        float2 p5 = __half22float2(y2[(size_t)c5 * 32 + f]);
        float2 p6 = __half22float2(y2[(size_t)c6 * 32 + f]);
        float2 p7 = __half22float2(y2[(size_t)c7 * 32 + f]);
        a0.x += p0.x + p4.x; a0.y += p0.y + p4.y;
        a1.x += p1.x + p5.x; a1.y += p1.y + p5.y;
        a2.x += p2.x + p6.x; a2.y += p2.y + p6.y;
        a3.x += p3.x + p7.x; a3.y += p3.y + p7.y;
    }
    for (; j < e; j += 8) {
        int4 ca = *(const int4*)(erow + j);
        int4 cb = *(const int4*)(erow + j + 4);
        int c0 = h ? ca.y : ca.x, c1 = h ? ca.w : ca.z;
        int c2 = h ? cb.y : cb.x, c3 = h ? cb.w : cb.z;
        float2 p0 = __half22float2(y2[(size_t)c0 * 32 + f]);
        float2 p1 = __half22float2(y2[(size_t)c1 * 32 + f]);
        float2 p2 = __half22float2(y2[(size_t)c2 * 32 + f]);
        float2 p3 = __half22float2(y2[(size_t)c3 * 32 + f]);
        a0.x += p0.x; a0.y += p0.y;
        a1.x += p1.x; a1.y += p1.y;
        a2.x += p2.x; a2.y += p2.y;
        a3.x += p3.x; a3.y += p3.y;
    }
    float sx = (a0.x + a1.x) + (a2.x + a3.x);
    float sy = (a0.y + a1.y) + (a2.y + a3.y);
    sx += __shfl_xor(sx, 32);
    sy += __shfl_xor(sy, 32);
    if (h == 0) {
        float d = dinv[r];
        float2 v = acc2[(size_t)t * 32 + f];
        v.x += d * sx;
        v.y += d * sy;
        acc2[(size_t)t * 32 + f] = v;
    }
}

// ---------- layer-0 acc: read embeddings directly (fp32 exact), first write ----------
__global__ void gather_acc0(const float* __restrict__ ue, const float* __restrict__ ie,
                            const int* __restrict__ uidx, const int* __restrict__ iidx,
                            float* __restrict__ acc, int nb, int nu) {
    int t = blockIdx.x * blockDim.x + threadIdx.x;
    int b = t >> 6;
    int lane = t & 63;
    if (b < nb) acc[t] = ue[(long)uidx[b] * DIM + lane];
    else if (b < 2 * nb) acc[t] = ie[(long)iidx[b - nb] * DIM + lane];
}

// ---------- layers 1,2 acc: x_l[r] = y_l[r] * sqrt(deg_r), half2-vectorized ----------
__global__ void gather_acc_y(const __half2* __restrict__ y2, const float* __restrict__ sqd,
                             const int* __restrict__ uidx, const int* __restrict__ iidx,
                             float2* __restrict__ acc2, int nb, int nu) {
    int t = blockIdx.x * blockDim.x + threadIdx.x;
    if (t >= 2 * nb * 32) return;
    int b = t >> 5;
    int r = (b < nb) ? uidx[b] : nu + iidx[b - nb];
    float s = sqd[r];
    float2 v = __half22float2(y2[(size_t)r * 32 + (t & 31)]);
    float2 a = acc2[t];
    a.x += v.x * s;
    a.y += v.y * s;
    acc2[t] = a;
}

// scores[b] = dot(acc_u[b], acc_i[b]) / 16
__global__ void scores_kernel(const float* __restrict__ acc, float* __restrict__ out, int nb) {
    int b = blockIdx.x * (blockDim.x >> 6) + (threadIdx.x >> 6);
    int lane = threadIdx.x & 63;
    if (b >= nb) return;
    float p = acc[(long)b * DIM + lane] * acc[(long)(nb + b) * DIM + lane];
    #pragma unroll
    for (int off = 32; off; off >>= 1) p += __shfl_down(p, off);
    if (lane == 0) out[b] = p * 0.0625f;
}

extern "C" void kernel_launch(void* const* d_in, const int* in_sizes, int n_in,
                              void* d_out, int out_size, void* d_ws, size_t ws_size,
                              hipStream_t stream) {
    const float* user_emb = (const float*)d_in[0];
    const float* item_emb = (const float*)d_in[1];
    const int* edge_row = (const int*)d_in[2];
    const int* edge_col = (const int*)d_in[3];
    const int* user_idx = (const int*)d_in[4];
    const int* item_idx = (const int*)d_in[5];
    float* out = (float*)d_out;

    const int nu = in_sizes[0] / DIM;   // 100000
    const int ni = in_sizes[1] / DIM;   // 50000
    const int nn = nu + ni;             // 150000
    const int ne = in_sizes[2];         // 3200000
    const int nb = in_sizes[4];         // 4096

    const int nbk = (nn + 255) >> BSH;              // 586 buckets
    const int chunk = (ne + NBLKA - 1) / NBLKA;     // 3125

    char* ws = (char*)d_ws;
    size_t off_b = 0;
    auto alloc = [&](size_t bytes) -> void* {
        void* p = ws + off_b;
        off_b = (off_b + bytes + 255) & ~(size_t)255;
        return p;
    };

    int*   cnt     = (int*)  alloc((size_t)nn * 4);
    int*   roff    = (int*)  alloc((size_t)nn * 4);
    float* dinv    = (float*)alloc((size_t)nn * 4);
    float* sqd     = (float*)alloc((size_t)nn * 4);
    unsigned char* flag = (unsigned char*)alloc((size_t)nn);
    int*   tot     = (int*)  alloc((size_t)MAXNB * NSH * 4);
    int*   blkoff  = (int*)  alloc((size_t)MAXNB * NSH * 128 * 4);   // shard-major [p][g]
    int*   csr     = (int*)  alloc((size_t)nbk * SCSR * 4);
    // bin (shard-partitioned, consumed by csr_build) unioned with ya (written after)
    size_t bin_bytes = (size_t)nbk * NSH * SBIN_SH * 4;   // ~28.8 MB
    size_t y_bytes   = (size_t)(nn + 1) * DIM * 2;        // +1 sentinel zero row
    char*  uni     = (char*) alloc(bin_bytes > y_bytes ? bin_bytes : y_bytes);
    unsigned int* bin = (unsigned int*)uni;
    __half2* ya    = (__half2*)uni;
    __half2* yb    = (__half2*)alloc(y_bytes);
    float* acc     = (float*)alloc((size_t)2 * nb * DIM * 4);

    hipMemsetAsync(flag, 0, (size_t)nn, stream);

    // --- binned CSR build: deterministic sharded offsets, zero global atomics ---
    binA1s<<<NBLKA, 256, 0, stream>>>(edge_row, blkoff, ne, chunk, nbk);
    scanS<<<nbk * NSH, 128, 0, stream>>>(blkoff, tot);
    binA2s<<<NBLKA, 256, 0, stream>>>(edge_row, edge_col, blkoff, bin, ne, chunk, nbk);
    csr_build<<<nbk, 512, 0, stream>>>(bin, tot, csr, cnt, roff, dinv, sqd, nn);

    // --- mark rows whose y2 is consumed (batch + neighbors) ---
    mark_kernel<<<(2 * nb + 3) / 4, 256, 0, stream>>>(cnt, roff, csr, user_idx, item_idx,
                                                      flag, nb, nu);

    // --- init y0 = half(dinv * emb); zero sentinel rows (overwrites bin region) ---
    init_y_kernel<<<((nn + 1) * 32 + 255) / 256, 256, 0, stream>>>(
        (const float2*)user_emb, (const float2*)item_emb, dinv, ya, yb, nu, nn);

    // --- layer 0 acc: exact fp32 embeddings ---
    gather_acc0<<<(2 * nb * DIM + 255) / 256, 256, 0, stream>>>(
        user_emb, item_emb, user_idx, item_idx, acc, nb, nu);

    // --- layer 1 (full) ---
    spmm_half_kernel<<<(nn + 3) / 4, 256, 0, stream>>>(cnt, roff, csr, dinv, ya, yb,
                                                       (const unsigned char*)nullptr, nn);
    gather_acc_y<<<(2 * nb * 32 + 255) / 256, 256, 0, stream>>>(
        yb, sqd, user_idx, item_idx, (float2*)acc, nb, nu);

    // --- layer 2 (restricted to flagged ~69% of rows) ---
    spmm_half_kernel<<<(nn + 3) / 4, 256, 0, stream>>>(cnt, roff, csr, dinv, yb, ya, flag, nn);
    gather_acc_y<<<(2 * nb * 32 + 255) / 256, 256, 0, stream>>>(
        ya, sqd, user_idx, item_idx, (float2*)acc, nb, nu);

    // --- layer 3: only the 8192 batch rows are ever read -> mini-SpMM into acc ---
    spmm_rows_acc_kernel<<<(2 * nb + 3) / 4, 256, 0, stream>>>(
        cnt, roff, csr, dinv, ya, user_idx, item_idx, (float2*)acc, nb, nu);

    scores_kernel<<<(nb + 3) / 4, 256, 0, stream>>>(acc, out, nb);
}